// Round 8
// baseline (110.894 us; speedup 1.0000x reference)
//
#include <hip/hip_runtime.h>
#include <math.h>

// Problem constants (B=4, S=2048, E=1024, A=64)
#define BATCH 4
#define SLEN  2048
#define EMB   1024
#define AH    64

typedef __attribute__((ext_vector_type(8))) short bf16x8;
typedef __attribute__((ext_vector_type(4))) float f32x4;

#define MFMA16(a, b, c) __builtin_amdgcn_mfma_f32_16x16x32_bf16((a), (b), (c), 0, 0, 0)

// async 16B global->LDS: zero VGPR cost, guaranteed in-flight batching.
// LDS dest = wave-uniform base + lane*16 (implicit).
__device__ __forceinline__ void async16(const void* g, void* l) {
  __builtin_amdgcn_global_load_lds(
      (const __attribute__((address_space(1))) unsigned int*)g,
      (__attribute__((address_space(3))) unsigned int*)l, 16, 0, 0);
}

__device__ __forceinline__ short f2bf(float x) {  // RNE
  union { float f; unsigned u; } v; v.f = x;
  unsigned r = v.u + 0x7fffu + ((v.u >> 16) & 1u);
  return (short)(r >> 16);
}
__device__ __forceinline__ float bf2f(short h) {
  union { unsigned u; float f; } v; v.u = ((unsigned)(unsigned short)h) << 16;
  return v.f;
}

// Truncate-split 8 fp32 -> bf16 hi (high16) + bf16 lo (trunc of residual).
__device__ __forceinline__ void split_trunc(float4 a0, float4 a1, bf16x8& hi, bf16x8& lo) {
  unsigned c[8] = {__float_as_uint(a0.x), __float_as_uint(a0.y), __float_as_uint(a0.z),
                   __float_as_uint(a0.w), __float_as_uint(a1.x), __float_as_uint(a1.y),
                   __float_as_uint(a1.z), __float_as_uint(a1.w)};
  union { bf16x8 v; unsigned d[4]; } H, L;
  H.d[0] = __builtin_amdgcn_perm(c[1], c[0], 0x07060302u);
  H.d[1] = __builtin_amdgcn_perm(c[3], c[2], 0x07060302u);
  H.d[2] = __builtin_amdgcn_perm(c[5], c[4], 0x07060302u);
  H.d[3] = __builtin_amdgcn_perm(c[7], c[6], 0x07060302u);
  unsigned e[8];
#pragma unroll
  for (int j = 0; j < 8; ++j)
    e[j] = __float_as_uint(__uint_as_float(c[j]) - __uint_as_float(c[j] & 0xffff0000u));
  L.d[0] = __builtin_amdgcn_perm(e[1], e[0], 0x07060302u);
  L.d[1] = __builtin_amdgcn_perm(e[3], e[2], 0x07060302u);
  L.d[2] = __builtin_amdgcn_perm(e[5], e[4], 0x07060302u);
  L.d[3] = __builtin_amdgcn_perm(e[7], e[6], 0x07060302u);
  hi = H.v; lo = L.v;
}

// Triangular chunk-slot offset: off(qt) = sum_{q<qt} (q/2 + 1)
__device__ __forceinline__ int slot_off(int qt) {
  return (qt == 0) ? 0 : qt + (((qt - 1) * (qt - 1)) >> 2);
}

// Kpack chunk layout (shorts), per (b, chunk of 128 keys), 24576 shorts = 48 KB:
//   [0,8192):      KBhi  [kb(8)][a32(2)][lane(64)][8]   S-MFMA B-frag, hi plane
//   [8192,16384):  KBlo  same, lo plane
//   [16384,24576): VB    [kc2(4)][nt(4)][lane(64)][8] PV-MFMA B-frag (hi only)
#define CH_SHORTS 24576

// ---------------------------------------------------------------------------
// Kernel 0: pack Wk [64,1024] fp32 -> BpkG [kc(32)][nt(4)][pl(2)][lane(64)][8]
// ---------------------------------------------------------------------------
__global__ __launch_bounds__(256) void prep_wk_kernel(const float* __restrict__ Wk,
                                                      short* __restrict__ BpkG) {
  int tg = blockIdx.x * 256 + threadIdx.x;  // 8192 = 32kc * 4nt * 64lane
  int kc = tg >> 8, rem = tg & 255, nt = rem >> 6, lane = rem & 63;
  int n = nt * 16 + (lane & 15);
  int k = kc * 32 + (lane >> 4) * 8;
  const float* src = Wk + (size_t)n * EMB + k;
  float4 a0 = *(const float4*)src;
  float4 a1 = *(const float4*)(src + 4);
  bf16x8 hi, lo;
  split_trunc(a0, a1, hi, lo);
  short* dst = BpkG + ((size_t)(kc * 4 + nt) * 128 + lane) * 8;  // pl=0
  *(bf16x8*)dst = hi;
  *(bf16x8*)(dst + 512) = lo;  // pl=1
}

// ---------------------------------------------------------------------------
// Kernel 1: K = emb @ Wk^T, DOUBLE-BUFFERED async LDS staging.
// 512 blocks x 256; BM=16, K-loop 16 steps of BK=64; two 20 KB buffers.
// stage(s+1) issues after barrier(s) and before compute(s), so the next
// barrier's vmcnt(0) drain overlaps a full compute phase.
// ---------------------------------------------------------------------------
__global__ __launch_bounds__(256) void gemm_k_kernel(const float* __restrict__ emb,
                                                     const short* __restrict__ BpkG,
                                                     short* __restrict__ Kpack) {
  __shared__ __align__(16) char glds[40960];  // 2 x (4 KB emb + 16 KB bpk)

  const int t = threadIdx.x;
  const int w = t >> 6, l = t & 63, lm = l & 15, quad = l >> 4;
  const int nt = w;
  const int row0 = blockIdx.x * 16;

  // stage step 'step' into buffer 'bs':
  //  emb: 16 rows x 64 floats; wave w covers rows 4w..4w+3; lane l -> row
  //  4w+(l>>4), 16B-unit position (l&15) holding unit (l&15)^(row&7).
  //  bpk: 16 KB slice (2 kc), 4 issues/wave, layout mirrored.
  auto stage = [&](int step, int bs) {
    char* base = glds + bs * 20480;
    float* eT = (float*)base;
    short* bT = (short*)(base + 4096);
    int rowl = 4 * w + (l >> 4);
    int du = (l & 15) ^ (rowl & 7);
    async16(emb + (size_t)(row0 + rowl) * EMB + step * 64 + du * 4, eT + w * 256);
    const short* bg = BpkG + (size_t)step * 8192;
#pragma unroll
    for (int u = 0; u < 4; ++u)
      async16(bg + (w * 4 + u) * 512 + l * 8, bT + (w * 4 + u) * 512);
  };

  f32x4 acc = {0.f, 0.f, 0.f, 0.f};
  stage(0, 0);
#pragma unroll
  for (int s = 0; s < 16; ++s) {
    __syncthreads();  // drains stage(s) (issued one compute-phase ago)
    if (s < 15) stage(s + 1, (s + 1) & 1);
    char* base = glds + (s & 1) * 20480;
    float* eT = (float*)base;
    short* bT = (short*)(base + 4096);
#pragma unroll
    for (int kc = 0; kc < 2; ++kc) {
      int du0 = kc * 8 + quad * 2;
      float4 a0 = *(const float4*)((char*)eT + lm * 256 + ((du0) ^ (lm & 7)) * 16);
      float4 a1 = *(const float4*)((char*)eT + lm * 256 + ((du0 + 1) ^ (lm & 7)) * 16);
      bf16x8 ahi, alo;
      split_trunc(a0, a1, ahi, alo);
      bf16x8 bhi = *(const bf16x8*)(bT + (((kc * 4 + nt) * 2 + 0) * 64 + l) * 8);
      bf16x8 blo = *(const bf16x8*)(bT + (((kc * 4 + nt) * 2 + 1) * 64 + l) * 8);
      acc = MFMA16(ahi, bhi, acc);
      acc = MFMA16(ahi, blo, acc);
      acc = MFMA16(alo, bhi, acc);
    }
  }

  // epilogue: C layout (row=quad*4+r, col a=nt*16+lm) -> Kpack fragment scatter
  const int a = nt * 16 + lm;
#pragma unroll
  for (int r = 0; r < 4; ++r) {
    int srow = row0 + quad * 4 + r;
    float v = acc[r];
    short h = f2bf(v);
    short lo2 = f2bf(v - bf2f(h));
    int bb = srow >> 11, si = srow & 2047, c = si >> 7, key = si & 127;
    int kb = key >> 4, klm = key & 15;
    size_t cb = (size_t)(bb * 16 + c) * CH_SHORTS;
    size_t kbo = (size_t)((kb * 2 + (a >> 5)) * 64 + ((a & 31) >> 3) * 16 + klm) * 8 + (a & 7);
    Kpack[cb + kbo] = h;
    Kpack[cb + 8192 + kbo] = lo2;
    size_t vbo = (size_t)(((key >> 5) * 4 + (a >> 4)) * 64 + ((key & 31) >> 3) * 16 + (a & 15)) * 8 + (key & 7);
    Kpack[cb + 16384 + vbo] = h;
  }
}

// ---------------------------------------------------------------------------
// Kernel 2: flash partials, TWO q-tiles per staged chunk.
// grid (16 chunks, 16 q-pairs, 4 b); active iff c <= g -> 544 blocks.
// Stage KBhi/KBlo (32 KB, 8 async issues/thread); Q frags (both tiles) and
// all 16 V frags prefetched direct-to-VGPR before the single barrier.
// ---------------------------------------------------------------------------
__global__ __launch_bounds__(256, 3) void flash_kernel(const short* __restrict__ Kpack,
                                                       short* __restrict__ OpartH,
                                                       float2* __restrict__ mlpart) {
  const int c = blockIdx.x, g = blockIdx.y, b = blockIdx.z;
  if (c > g) return;

  __shared__ __align__(16) short KLs[16384];        // KBhi+KBlo of chunk c (32 KB)
  __shared__ __align__(16) short Plds[4][16][132];  // per-wave P buffers (16.5 KB)

  const int t = threadIdx.x;
  const int w = t >> 6, l = t & 63, lm = l & 15, quad = l >> 4;
  const int k0 = c * 128;

  const short* chunkG = Kpack + (size_t)(b * 16 + c) * CH_SHORTS;
  // stage KBhi + KBlo: 32 slots x 1 KB
#pragma unroll
  for (int u = 0; u < 8; ++u) {
    int slot = w * 8 + u;
    async16(chunkG + slot * 512 + l * 8, KLs + slot * 512);
  }

  // prefetch Q fragments for both q-tiles (rows live in chunk g's KB region)
  const short* qGb = Kpack + (size_t)(b * 16 + g) * CH_SHORTS;
  bf16x8 qh0[2], qh1[2], ql0[2], ql1[2];
#pragma unroll
  for (int qi = 0; qi < 2; ++qi) {
    const short* qG = qGb + (qi * 4 + w) * 1024;
    qh0[qi] = *(const bf16x8*)(qG + l * 8);
    qh1[qi] = *(const bf16x8*)(qG + 512 + l * 8);
    ql0[qi] = *(const bf16x8*)(qG + 8192 + l * 8);
    ql1[qi] = *(const bf16x8*)(qG + 8192 + 512 + l * 8);
  }

  // prefetch all 16 V fragments direct from global (coalesced 16B/lane)
  bf16x8 vf[4][4];
#pragma unroll
  for (int kc2 = 0; kc2 < 4; ++kc2)
#pragma unroll
    for (int nt = 0; nt < 4; ++nt)
      vf[kc2][nt] = *(const bf16x8*)(chunkG + 16384 + ((kc2 * 4 + nt) * 64 + l) * 8);

  __syncthreads();  // drains staging (and the Q/V register loads)

#pragma unroll
  for (int qi = 0; qi < 2; ++qi) {
    const int qt = 2 * g + qi;
    const int qr0 = qt * 64 + w * 16;

    // S = Q K^T: 8 key-groups x 2 a-chunks x split(hh+hl+lh)
    f32x4 sc[8];
#pragma unroll
    for (int kg = 0; kg < 8; ++kg) {
      bf16x8 bh0 = *(const bf16x8*)(KLs + ((kg * 2 + 0) * 64 + l) * 8);
      bf16x8 bh1 = *(const bf16x8*)(KLs + ((kg * 2 + 1) * 64 + l) * 8);
      bf16x8 bl0 = *(const bf16x8*)(KLs + 8192 + ((kg * 2 + 0) * 64 + l) * 8);
      bf16x8 bl1 = *(const bf16x8*)(KLs + 8192 + ((kg * 2 + 1) * 64 + l) * 8);
      f32x4 s = {0.f, 0.f, 0.f, 0.f};
      s = MFMA16(qh0[qi], bh0, s);
      s = MFMA16(qh0[qi], bl0, s);
      s = MFMA16(ql0[qi], bh0, s);
      s = MFMA16(qh1[qi], bh1, s);
      s = MFMA16(qh1[qi], bl1, s);
      s = MFMA16(ql1[qi], bh1, s);
      sc[kg] = s;
    }

    // mask + single-pass softmax (C layout: row=quad*4+r, col=kg*16+lm)
    float rm[4] = {-INFINITY, -INFINITY, -INFINITY, -INFINITY};
#pragma unroll
    for (int kg = 0; kg < 8; ++kg) {
      const int col = k0 + kg * 16 + lm;
#pragma unroll
      for (int r = 0; r < 4; ++r) {
        const int row = qr0 + quad * 4 + r;
        float v = sc[kg][r] * 0.125f;
        v = (col > row || v == 0.0f) ? -INFINITY : v;
        sc[kg][r] = v;
        rm[r] = fmaxf(rm[r], v);
      }
    }
    float m_i[4], l_i[4];
#pragma unroll
    for (int r = 0; r < 4; ++r) {
      for (int off = 1; off < 16; off <<= 1) rm[r] = fmaxf(rm[r], __shfl_xor(rm[r], off, 16));
      m_i[r] = rm[r];
    }
    float rs[4] = {0.f, 0.f, 0.f, 0.f};
#pragma unroll
    for (int kg = 0; kg < 8; ++kg)
#pragma unroll
      for (int r = 0; r < 4; ++r) {
        float p = (sc[kg][r] == -INFINITY) ? 0.f : __expf(sc[kg][r] - m_i[r]);
        sc[kg][r] = p;
        rs[r] += p;
      }
#pragma unroll
    for (int r = 0; r < 4; ++r) {
      for (int off = 1; off < 16; off <<= 1) rs[r] += __shfl_xor(rs[r], off, 16);
      l_i[r] = rs[r];
    }

    // P -> Plds (C layout -> A-operand layout), per-wave private, no barrier
#pragma unroll
    for (int kg = 0; kg < 8; ++kg)
#pragma unroll
      for (int r = 0; r < 4; ++r)
        Plds[w][quad * 4 + r][kg * 16 + lm] = f2bf(sc[kg][r]);

    // O = P V over 128 keys (V fragments already in registers)
    f32x4 o[4] = {{0.f,0.f,0.f,0.f},{0.f,0.f,0.f,0.f},{0.f,0.f,0.f,0.f},{0.f,0.f,0.f,0.f}};
#pragma unroll
    for (int kc2 = 0; kc2 < 4; ++kc2) {
      bf16x8 pf = *(const bf16x8*)&Plds[w][lm][kc2 * 32 + quad * 8];
#pragma unroll
      for (int nt = 0; nt < 4; ++nt)
        o[nt] = MFMA16(pf, vf[kc2][nt], o[nt]);
    }

    // write partials: bf16 O (contiguous 8 KB/block) + packed (m,l)
    const int slot = b * 272 + slot_off(qt) + c;
    short* Ob = OpartH + (size_t)slot * 4096;
#pragma unroll
    for (int nt = 0; nt < 4; ++nt)
#pragma unroll
      for (int r = 0; r < 4; ++r)
        Ob[(size_t)(w * 16 + quad * 4 + r) * AH + nt * 16 + lm] = f2bf(o[nt][r]);
    if (lm == 0) {
#pragma unroll
      for (int r = 0; r < 4; ++r)
        mlpart[(size_t)slot * 64 + w * 16 + quad * 4 + r] = make_float2(m_i[r], l_i[r]);
    }
  }
}

// ---------------------------------------------------------------------------
// Kernel 3: merge via async LDS staging. grid (4 rowgroups, 32 qt, 4 b).
// ---------------------------------------------------------------------------
__global__ __launch_bounds__(256) void merge_kernel(const short* __restrict__ OpartH,
                                                    const float2* __restrict__ mlpart,
                                                    float* __restrict__ out) {
  __shared__ __align__(16) short ldsO[16 * 1024];  // [chunk(16)][row(16)][a(64)] bf16
  __shared__ float wtab[16][17];                   // [row][chunk] weight/L
  const int t = threadIdx.x;
  const int w = t >> 6, l = t & 63;
  const int rg = blockIdx.x, qt = blockIdx.y, b = blockIdx.z;
  const int r0 = rg * 16;
  const int nch = (qt >> 1) + 1;
  const int slotbase = b * 272 + slot_off(qt);

#pragma unroll
  for (int u = 0; u < 8; ++u) {
    int idx = w * 8 + u;  // 32 issues x 1 KB
    int c = idx >> 1, half = idx & 1;
    if (c < nch)  // wave-uniform predicate
      async16(OpartH + (size_t)(slotbase + c) * 4096 + r0 * 64 + half * 512 + l * 8,
              ldsO + c * 1024 + half * 512 + l * 8);
  }

  const int row = w * 4 + (l >> 4), c = l & 15;
  float mc = -INFINITY, lc = 0.f;
  if (c < nch) {
    float2 ml = mlpart[(size_t)(slotbase + c) * 64 + r0 + row];
    mc = ml.x; lc = ml.y;
  }
  float M = mc;
  for (int off = 1; off < 16; off <<= 1) M = fmaxf(M, __shfl_xor(M, off, 16));
  float wgt = (mc != -INFINITY) ? __expf(mc - M) : 0.f;
  float L = lc * wgt;
  for (int off = 1; off < 16; off <<= 1) L += __shfl_xor(L, off, 16);
  wtab[row][c] = wgt / L;

  __syncthreads();  // drains async staging; wtab visible

  const int row2 = t >> 4, a0 = (t & 15) * 4;
  float4 acc = make_float4(0.f, 0.f, 0.f, 0.f);
  for (int cc = 0; cc < nch; ++cc) {
    float wv = wtab[row2][cc];
    short4 v4 = *(const short4*)(ldsO + cc * 1024 + row2 * 64 + a0);
    acc.x += wv * bf2f(v4.x); acc.y += wv * bf2f(v4.y);
    acc.z += wv * bf2f(v4.z); acc.w += wv * bf2f(v4.w);
  }
  *(float4*)&out[((size_t)(b * 2048 + qt * 64 + r0 + row2)) * AH + a0] = acc;
}

// ---------------------------------------------------------------------------
// Workspace (bytes):
//   Kpack   [0,        3145728)    4 b x 16 chunks x 48 KB
//   BpkG    [3145728,  3670016)    256 KB (+slack)
//   OpartH  [3670016,  12582912)   1088 slots x 4096 bf16
//   mlpart  [12582912, 13139968)   1088 x 64 float2
// ---------------------------------------------------------------------------
extern "C" void kernel_launch(void* const* d_in, const int* in_sizes, int n_in,
                              void* d_out, int out_size, void* d_ws, size_t ws_size,
                              hipStream_t stream) {
  const float* emb = (const float*)d_in[0];
  const float* Wk  = (const float*)d_in[1];
  float* out = (float*)d_out;
  char* ws = (char*)d_ws;

  short*  Kpack  = (short*)(ws);
  short*  BpkG   = (short*)(ws + 3145728);
  short*  OpartH = (short*)(ws + 3670016);
  float2* mlpart = (float2*)(ws + 12582912);

  prep_wk_kernel<<<dim3(32), dim3(256), 0, stream>>>(Wk, BpkG);
  gemm_k_kernel<<<dim3(512), dim3(256), 0, stream>>>(emb, BpkG, Kpack);
  flash_kernel<<<dim3(16, 16, 4), dim3(256), 0, stream>>>(Kpack, OpartH, mlpart);
  merge_kernel<<<dim3(4, 32, 4), dim3(256), 0, stream>>>(OpartH, mlpart, out);
}

// Round 9
// 106.945 us; speedup vs baseline: 1.0369x; 1.0369x over previous
//
#include <hip/hip_runtime.h>
#include <math.h>

// Problem constants (B=4, S=2048, E=1024, A=64)
#define BATCH 4
#define SLEN  2048
#define EMB   1024
#define AH    64

typedef __attribute__((ext_vector_type(8))) short bf16x8;
typedef __attribute__((ext_vector_type(4))) float f32x4;

#define MFMA16(a, b, c) __builtin_amdgcn_mfma_f32_16x16x32_bf16((a), (b), (c), 0, 0, 0)

// async 16B global->LDS: zero VGPR cost, guaranteed in-flight batching.
// LDS dest = wave-uniform base + lane*16 (implicit).
__device__ __forceinline__ void async16(const void* g, void* l) {
  __builtin_amdgcn_global_load_lds(
      (const __attribute__((address_space(1))) unsigned int*)g,
      (__attribute__((address_space(3))) unsigned int*)l, 16, 0, 0);
}

__device__ __forceinline__ short f2bf(float x) {  // RNE
  union { float f; unsigned u; } v; v.f = x;
  unsigned r = v.u + 0x7fffu + ((v.u >> 16) & 1u);
  return (short)(r >> 16);
}
__device__ __forceinline__ float bf2f(short h) {
  union { unsigned u; float f; } v; v.u = ((unsigned)(unsigned short)h) << 16;
  return v.f;
}

// Truncate-split 8 fp32 -> bf16 hi (high16) + bf16 lo (trunc of residual).
__device__ __forceinline__ void split_trunc(float4 a0, float4 a1, bf16x8& hi, bf16x8& lo) {
  unsigned c[8] = {__float_as_uint(a0.x), __float_as_uint(a0.y), __float_as_uint(a0.z),
                   __float_as_uint(a0.w), __float_as_uint(a1.x), __float_as_uint(a1.y),
                   __float_as_uint(a1.z), __float_as_uint(a1.w)};
  union { bf16x8 v; unsigned d[4]; } H, L;
  H.d[0] = __builtin_amdgcn_perm(c[1], c[0], 0x07060302u);
  H.d[1] = __builtin_amdgcn_perm(c[3], c[2], 0x07060302u);
  H.d[2] = __builtin_amdgcn_perm(c[5], c[4], 0x07060302u);
  H.d[3] = __builtin_amdgcn_perm(c[7], c[6], 0x07060302u);
  unsigned e[8];
#pragma unroll
  for (int j = 0; j < 8; ++j)
    e[j] = __float_as_uint(__uint_as_float(c[j]) - __uint_as_float(c[j] & 0xffff0000u));
  L.d[0] = __builtin_amdgcn_perm(e[1], e[0], 0x07060302u);
  L.d[1] = __builtin_amdgcn_perm(e[3], e[2], 0x07060302u);
  L.d[2] = __builtin_amdgcn_perm(e[5], e[4], 0x07060302u);
  L.d[3] = __builtin_amdgcn_perm(e[7], e[6], 0x07060302u);
  hi = H.v; lo = L.v;
}

// Triangular chunk-slot offset: off(qt) = sum_{q<qt} (q/2 + 1)
__device__ __forceinline__ int slot_off(int qt) {
  return (qt == 0) ? 0 : qt + (((qt - 1) * (qt - 1)) >> 2);
}

// Kpack chunk layout (shorts), per (b, chunk of 128 keys), 24576 shorts = 48 KB:
//   [0,8192):      KBhi  [kb(8)][a32(2)][lane(64)][8]   S-MFMA B-frag, hi plane
//   [8192,16384):  KBlo  same, lo plane
//   [16384,24576): VB    [kc2(4)][nt(4)][lane(64)][8] PV-MFMA B-frag (hi only)
#define CH_SHORTS 24576

// ---------------------------------------------------------------------------
// Kernel 0: pack Wk [64,1024] fp32 -> BpkG [kc(32)][nt(4)][pl(2)][lane(64)][8]
// ---------------------------------------------------------------------------
__global__ __launch_bounds__(256) void prep_wk_kernel(const float* __restrict__ Wk,
                                                      short* __restrict__ BpkG) {
  int tg = blockIdx.x * 256 + threadIdx.x;  // 8192 = 32kc * 4nt * 64lane
  int kc = tg >> 8, rem = tg & 255, nt = rem >> 6, lane = rem & 63;
  int n = nt * 16 + (lane & 15);
  int k = kc * 32 + (lane >> 4) * 8;
  const float* src = Wk + (size_t)n * EMB + k;
  float4 a0 = *(const float4*)src;
  float4 a1 = *(const float4*)(src + 4);
  bf16x8 hi, lo;
  split_trunc(a0, a1, hi, lo);
  short* dst = BpkG + ((size_t)(kc * 4 + nt) * 128 + lane) * 8;  // pl=0
  *(bf16x8*)dst = hi;
  *(bf16x8*)(dst + 512) = lo;  // pl=1
}

// ---------------------------------------------------------------------------
// Kernel 1: K = emb @ Wk^T, DOUBLE-BUFFERED async LDS staging.
// 512 blocks x 256; BM=16, K-loop 16 steps of BK=64; two 20 KB buffers.
// ---------------------------------------------------------------------------
__global__ __launch_bounds__(256) void gemm_k_kernel(const float* __restrict__ emb,
                                                     const short* __restrict__ BpkG,
                                                     short* __restrict__ Kpack) {
  __shared__ __align__(16) char glds[40960];  // 2 x (4 KB emb + 16 KB bpk)

  const int t = threadIdx.x;
  const int w = t >> 6, l = t & 63, lm = l & 15, quad = l >> 4;
  const int nt = w;
  const int row0 = blockIdx.x * 16;

  auto stage = [&](int step, int bs) {
    char* base = glds + bs * 20480;
    float* eT = (float*)base;
    short* bT = (short*)(base + 4096);
    int rowl = 4 * w + (l >> 4);
    int du = (l & 15) ^ (rowl & 7);
    async16(emb + (size_t)(row0 + rowl) * EMB + step * 64 + du * 4, eT + w * 256);
    const short* bg = BpkG + (size_t)step * 8192;
#pragma unroll
    for (int u = 0; u < 4; ++u)
      async16(bg + (w * 4 + u) * 512 + l * 8, bT + (w * 4 + u) * 512);
  };

  f32x4 acc = {0.f, 0.f, 0.f, 0.f};
  stage(0, 0);
#pragma unroll
  for (int s = 0; s < 16; ++s) {
    __syncthreads();  // drains stage(s) (issued one compute-phase ago)
    if (s < 15) stage(s + 1, (s + 1) & 1);
    char* base = glds + (s & 1) * 20480;
    float* eT = (float*)base;
    short* bT = (short*)(base + 4096);
#pragma unroll
    for (int kc = 0; kc < 2; ++kc) {
      int du0 = kc * 8 + quad * 2;
      float4 a0 = *(const float4*)((char*)eT + lm * 256 + ((du0) ^ (lm & 7)) * 16);
      float4 a1 = *(const float4*)((char*)eT + lm * 256 + ((du0 + 1) ^ (lm & 7)) * 16);
      bf16x8 ahi, alo;
      split_trunc(a0, a1, ahi, alo);
      bf16x8 bhi = *(const bf16x8*)(bT + (((kc * 4 + nt) * 2 + 0) * 64 + l) * 8);
      bf16x8 blo = *(const bf16x8*)(bT + (((kc * 4 + nt) * 2 + 1) * 64 + l) * 8);
      acc = MFMA16(ahi, bhi, acc);
      acc = MFMA16(ahi, blo, acc);
      acc = MFMA16(alo, bhi, acc);
    }
  }

  // epilogue: C layout (row=quad*4+r, col a=nt*16+lm) -> Kpack fragment scatter
  const int a = nt * 16 + lm;
#pragma unroll
  for (int r = 0; r < 4; ++r) {
    int srow = row0 + quad * 4 + r;
    float v = acc[r];
    short h = f2bf(v);
    short lo2 = f2bf(v - bf2f(h));
    int bb = srow >> 11, si = srow & 2047, c = si >> 7, key = si & 127;
    int kb = key >> 4, klm = key & 15;
    size_t cb = (size_t)(bb * 16 + c) * CH_SHORTS;
    size_t kbo = (size_t)((kb * 2 + (a >> 5)) * 64 + ((a & 31) >> 3) * 16 + klm) * 8 + (a & 7);
    Kpack[cb + kbo] = h;
    Kpack[cb + 8192 + kbo] = lo2;
    size_t vbo = (size_t)(((key >> 5) * 4 + (a >> 4)) * 64 + ((key & 31) >> 3) * 16 + (a & 15)) * 8 + (key & 7);
    Kpack[cb + 16384 + vbo] = h;
  }
}

// ---------------------------------------------------------------------------
// Kernel 2: flash partials. grid (16 chunks, 32 qt, 4 b); active iff
// 2c <= qt -> 1088 blocks (4.25/CU demand, 3 resident at 49.7 KB LDS).
// Stage KBhi/KBlo (32 KB, 8 async issues/thread); Q frags and all 16 V
// frags prefetched direct-to-VGPR before the single barrier.
// ---------------------------------------------------------------------------
__global__ __launch_bounds__(256, 3) void flash_kernel(const short* __restrict__ Kpack,
                                                       short* __restrict__ OpartH,
                                                       float2* __restrict__ mlpart) {
  const int c = blockIdx.x, qt = blockIdx.y, b = blockIdx.z;
  if (2 * c > qt) return;

  __shared__ __align__(16) short KLs[16384];        // KBhi+KBlo of chunk c (32 KB)
  __shared__ __align__(16) short Plds[4][16][132];  // per-wave P buffers (16.5 KB)

  const int t = threadIdx.x;
  const int w = t >> 6, l = t & 63, lm = l & 15, quad = l >> 4;
  const int k0 = c * 128;
  const int qr0 = qt * 64 + w * 16;

  const short* chunkG = Kpack + (size_t)(b * 16 + c) * CH_SHORTS;
  // stage KBhi + KBlo: 32 slots x 1 KB
#pragma unroll
  for (int u = 0; u < 8; ++u) {
    int slot = w * 8 + u;
    async16(chunkG + slot * 512 + l * 8, KLs + slot * 512);
  }

  // Q fragments direct-to-VGPR (rows live in chunk qt>>1's KB region)
  const short* qG = Kpack + (size_t)(b * 16 + (qt >> 1)) * CH_SHORTS + ((qt & 1) * 4 + w) * 1024;
  bf16x8 qh0 = *(const bf16x8*)(qG + l * 8);
  bf16x8 qh1 = *(const bf16x8*)(qG + 512 + l * 8);
  bf16x8 ql0 = *(const bf16x8*)(qG + 8192 + l * 8);
  bf16x8 ql1 = *(const bf16x8*)(qG + 8192 + 512 + l * 8);

  // all 16 V fragments direct from global (coalesced 16B/lane)
  bf16x8 vf[4][4];
#pragma unroll
  for (int kc2 = 0; kc2 < 4; ++kc2)
#pragma unroll
    for (int nt = 0; nt < 4; ++nt)
      vf[kc2][nt] = *(const bf16x8*)(chunkG + 16384 + ((kc2 * 4 + nt) * 64 + l) * 8);

  __syncthreads();  // drains staging (Q/V register loads also complete)

  // S = Q K^T: 8 key-groups x 2 a-chunks x split(hh+hl+lh)
  f32x4 sc[8];
#pragma unroll
  for (int kg = 0; kg < 8; ++kg) {
    bf16x8 bh0 = *(const bf16x8*)(KLs + ((kg * 2 + 0) * 64 + l) * 8);
    bf16x8 bh1 = *(const bf16x8*)(KLs + ((kg * 2 + 1) * 64 + l) * 8);
    bf16x8 bl0 = *(const bf16x8*)(KLs + 8192 + ((kg * 2 + 0) * 64 + l) * 8);
    bf16x8 bl1 = *(const bf16x8*)(KLs + 8192 + ((kg * 2 + 1) * 64 + l) * 8);
    f32x4 s = {0.f, 0.f, 0.f, 0.f};
    s = MFMA16(qh0, bh0, s);
    s = MFMA16(qh0, bl0, s);
    s = MFMA16(ql0, bh0, s);
    s = MFMA16(qh1, bh1, s);
    s = MFMA16(qh1, bl1, s);
    s = MFMA16(ql1, bh1, s);
    sc[kg] = s;
  }

  // mask + single-pass softmax (C layout: row=quad*4+r, col=kg*16+lm)
  float rm[4] = {-INFINITY, -INFINITY, -INFINITY, -INFINITY};
#pragma unroll
  for (int kg = 0; kg < 8; ++kg) {
    const int col = k0 + kg * 16 + lm;
#pragma unroll
    for (int r = 0; r < 4; ++r) {
      const int row = qr0 + quad * 4 + r;
      float v = sc[kg][r] * 0.125f;
      v = (col > row || v == 0.0f) ? -INFINITY : v;
      sc[kg][r] = v;
      rm[r] = fmaxf(rm[r], v);
    }
  }
  float m_i[4], l_i[4];
#pragma unroll
  for (int r = 0; r < 4; ++r) {
    for (int off = 1; off < 16; off <<= 1) rm[r] = fmaxf(rm[r], __shfl_xor(rm[r], off, 16));
    m_i[r] = rm[r];
  }
  float rs[4] = {0.f, 0.f, 0.f, 0.f};
#pragma unroll
  for (int kg = 0; kg < 8; ++kg)
#pragma unroll
    for (int r = 0; r < 4; ++r) {
      float p = (sc[kg][r] == -INFINITY) ? 0.f : __expf(sc[kg][r] - m_i[r]);
      sc[kg][r] = p;
      rs[r] += p;
    }
#pragma unroll
  for (int r = 0; r < 4; ++r) {
    for (int off = 1; off < 16; off <<= 1) rs[r] += __shfl_xor(rs[r], off, 16);
    l_i[r] = rs[r];
  }

  // P -> Plds (C layout -> A-operand layout), per-wave private, no barrier
#pragma unroll
  for (int kg = 0; kg < 8; ++kg)
#pragma unroll
    for (int r = 0; r < 4; ++r)
      Plds[w][quad * 4 + r][kg * 16 + lm] = f2bf(sc[kg][r]);

  // O = P V over 128 keys (V fragments already in registers)
  f32x4 o[4] = {{0.f,0.f,0.f,0.f},{0.f,0.f,0.f,0.f},{0.f,0.f,0.f,0.f},{0.f,0.f,0.f,0.f}};
#pragma unroll
  for (int kc2 = 0; kc2 < 4; ++kc2) {
    bf16x8 pf = *(const bf16x8*)&Plds[w][lm][kc2 * 32 + quad * 8];
#pragma unroll
    for (int nt = 0; nt < 4; ++nt)
      o[nt] = MFMA16(pf, vf[kc2][nt], o[nt]);
  }

  // write partials: bf16 O (contiguous 8 KB/block) + packed (m,l)
  const int slot = b * 272 + slot_off(qt) + c;
  short* Ob = OpartH + (size_t)slot * 4096;
#pragma unroll
  for (int nt = 0; nt < 4; ++nt)
#pragma unroll
    for (int r = 0; r < 4; ++r)
      Ob[(size_t)(w * 16 + quad * 4 + r) * AH + nt * 16 + lm] = f2bf(o[nt][r]);
  if (lm == 0) {
#pragma unroll
    for (int r = 0; r < 4; ++r)
      mlpart[(size_t)slot * 64 + w * 16 + quad * 4 + r] = make_float2(m_i[r], l_i[r]);
  }
}

// ---------------------------------------------------------------------------
// Kernel 3: merge via async LDS staging. grid (4 rowgroups, 32 qt, 4 b).
// ---------------------------------------------------------------------------
__global__ __launch_bounds__(256) void merge_kernel(const short* __restrict__ OpartH,
                                                    const float2* __restrict__ mlpart,
                                                    float* __restrict__ out) {
  __shared__ __align__(16) short ldsO[16 * 1024];  // [chunk(16)][row(16)][a(64)] bf16
  __shared__ float wtab[16][17];                   // [row][chunk] weight/L
  const int t = threadIdx.x;
  const int w = t >> 6, l = t & 63;
  const int rg = blockIdx.x, qt = blockIdx.y, b = blockIdx.z;
  const int r0 = rg * 16;
  const int nch = (qt >> 1) + 1;
  const int slotbase = b * 272 + slot_off(qt);

#pragma unroll
  for (int u = 0; u < 8; ++u) {
    int idx = w * 8 + u;  // 32 issues x 1 KB
    int c = idx >> 1, half = idx & 1;
    if (c < nch)  // wave-uniform predicate
      async16(OpartH + (size_t)(slotbase + c) * 4096 + r0 * 64 + half * 512 + l * 8,
              ldsO + c * 1024 + half * 512 + l * 8);
  }

  const int row = w * 4 + (l >> 4), c = l & 15;
  float mc = -INFINITY, lc = 0.f;
  if (c < nch) {
    float2 ml = mlpart[(size_t)(slotbase + c) * 64 + r0 + row];
    mc = ml.x; lc = ml.y;
  }
  float M = mc;
  for (int off = 1; off < 16; off <<= 1) M = fmaxf(M, __shfl_xor(M, off, 16));
  float wgt = (mc != -INFINITY) ? __expf(mc - M) : 0.f;
  float L = lc * wgt;
  for (int off = 1; off < 16; off <<= 1) L += __shfl_xor(L, off, 16);
  wtab[row][c] = wgt / L;

  __syncthreads();  // drains async staging; wtab visible

  const int row2 = t >> 4, a0 = (t & 15) * 4;
  float4 acc = make_float4(0.f, 0.f, 0.f, 0.f);
  for (int cc = 0; cc < nch; ++cc) {
    float wv = wtab[row2][cc];
    short4 v4 = *(const short4*)(ldsO + cc * 1024 + row2 * 64 + a0);
    acc.x += wv * bf2f(v4.x); acc.y += wv * bf2f(v4.y);
    acc.z += wv * bf2f(v4.z); acc.w += wv * bf2f(v4.w);
  }
  *(float4*)&out[((size_t)(b * 2048 + qt * 64 + r0 + row2)) * AH + a0] = acc;
}

// ---------------------------------------------------------------------------
// Workspace (bytes):
//   Kpack   [0,        3145728)    4 b x 16 chunks x 48 KB
//   BpkG    [3145728,  3670016)    256 KB (+slack)
//   OpartH  [3670016,  12582912)   1088 slots x 4096 bf16
//   mlpart  [12582912, 13139968)   1088 x 64 float2
// ---------------------------------------------------------------------------
extern "C" void kernel_launch(void* const* d_in, const int* in_sizes, int n_in,
                              void* d_out, int out_size, void* d_ws, size_t ws_size,
                              hipStream_t stream) {
  const float* emb = (const float*)d_in[0];
  const float* Wk  = (const float*)d_in[1];
  float* out = (float*)d_out;
  char* ws = (char*)d_ws;

  short*  Kpack  = (short*)(ws);
  short*  BpkG   = (short*)(ws + 3145728);
  short*  OpartH = (short*)(ws + 3670016);
  float2* mlpart = (float2*)(ws + 12582912);

  prep_wk_kernel<<<dim3(32), dim3(256), 0, stream>>>(Wk, BpkG);
  gemm_k_kernel<<<dim3(512), dim3(256), 0, stream>>>(emb, BpkG, Kpack);
  flash_kernel<<<dim3(16, 32, 4), dim3(256), 0, stream>>>(Kpack, OpartH, mlpart);
  merge_kernel<<<dim3(4, 32, 4), dim3(256), 0, stream>>>(OpartH, mlpart, out);
}